// Round 2
// baseline (309.107 us; speedup 1.0000x reference)
//
#include <hip/hip_runtime.h>

constexpr int EMB_DIM   = 300;   // = 75 float4 chunks, rows are 16B-aligned (1200 B)
constexpr int HIDDEN    = 256;
constexpr int OUT_DIM   = 3;
constexpr int SEQ       = 128;
constexpr int N_ASPECTS = 8;
constexpr int TILE      = 32;    // samples per MLP block

// meta layout (ints): [0..8) cnt, [8..17) base (base[8]=total), [32..40) cursor
#define META_CNT    0
#define META_BASE   8
#define META_CURSOR 32

// ---------------------------------------------------------------------------
// Pool: one sample per WAVE, float4 row reads. Lane l accumulates chunk l
// (all 64 lanes) and chunk 64+l (lanes 0..10): 75 chunks = 300 floats.
// 16 B/lane/instr -> 1 KB per wave load, ~8 KB in flight with unroll.
// ---------------------------------------------------------------------------
__global__ __launch_bounds__(256) void pool_kernel(
    const int* __restrict__ ids, const float* __restrict__ emb,
    float* __restrict__ x, int B) {
  const int wave = threadIdx.x >> 6;
  const int lane = threadIdx.x & 63;
  const int b = blockIdx.x * 4 + wave;
  if (b >= B) return;

  __shared__ int sid[4][SEQ];
  sid[wave][lane]      = ids[(size_t)b * SEQ + lane];
  sid[wave][lane + 64] = ids[(size_t)b * SEQ + lane + 64];
  // same-wave LDS RAW: compiler inserts lgkmcnt; waves are independent.

  float4 accA = make_float4(0.f, 0.f, 0.f, 0.f);
  float4 accB = make_float4(0.f, 0.f, 0.f, 0.f);
#pragma unroll 4
  for (int s = 0; s < SEQ; ++s) {
    const float4* __restrict__ r =
        (const float4*)(emb + (size_t)sid[wave][s] * EMB_DIM);
    float4 va = r[lane];
    accA.x += va.x; accA.y += va.y; accA.z += va.z; accA.w += va.w;
    if (lane < 11) {
      float4 vb = r[64 + lane];
      accB.x += vb.x; accB.y += vb.y; accB.z += vb.z; accB.w += vb.w;
    }
  }
  const float sc = 1.0f / (float)SEQ;
  float4* __restrict__ xr = (float4*)(x + (size_t)b * EMB_DIM);
  xr[lane] = make_float4(accA.x * sc, accA.y * sc, accA.z * sc, accA.w * sc);
  if (lane < 11)
    xr[64 + lane] = make_float4(accB.x * sc, accB.y * sc, accB.z * sc, accB.w * sc);
}

// ---------------------------------------------------------------------------
// Bucketing: count -> padded prefix -> scatter. Order within a bucket is
// nondeterministic (atomics) but each sample is written once to its own
// out[] slot, so the OUTPUT is deterministic.
// ---------------------------------------------------------------------------
__global__ void init_kernel(int* meta, int* perm, int nperm) {
  int i = blockIdx.x * 256 + threadIdx.x;
  if (i < nperm) perm[i] = -1;
  if (i < N_ASPECTS) { meta[META_CNT + i] = 0; meta[META_CURSOR + i] = 0; }
}

__global__ void count_kernel(const int* __restrict__ aspect, int* meta, int B) {
  int b = blockIdx.x * 256 + threadIdx.x;
  if (b < B) atomicAdd(&meta[META_CNT + aspect[b]], 1);
}

__global__ void prefix_kernel(int* meta) {
  if (threadIdx.x == 0 && blockIdx.x == 0) {
    int base = 0;
    for (int a = 0; a < N_ASPECTS; ++a) {
      meta[META_BASE + a] = base;
      meta[META_CURSOR + a] = base;
      int c = meta[META_CNT + a];
      base += ((c + TILE - 1) / TILE) * TILE;   // pad each bucket to TILE
    }
    meta[META_BASE + N_ASPECTS] = base;
  }
}

__global__ void scatter_kernel(const int* __restrict__ aspect, int* meta,
                               int* perm, int B) {
  int b = blockIdx.x * 256 + threadIdx.x;
  if (b < B) {
    int a = aspect[b];
    int pos = atomicAdd(&meta[META_CURSOR + a], 1);
    perm[pos] = b;
  }
}

// ---------------------------------------------------------------------------
// Routed MLP, 32 same-aspect samples per block. Thread j owns h-column j for
// all 32 samples: per weight W1[a][d][j] (read ONCE per block, coalesced)
// do 32 FMAs against sxT[d][0..31] (uniform-address b128 broadcasts).
// ---------------------------------------------------------------------------
__global__ __launch_bounds__(256) void mlp_kernel(
    const float* __restrict__ x, const int* __restrict__ aspect,
    const int* __restrict__ perm,
    const float* __restrict__ W1, const float* __restrict__ b1,
    const float* __restrict__ W2, const float* __restrict__ b2,
    float* __restrict__ out) {
  const int t = threadIdx.x;
  const int start = blockIdx.x * TILE;

  __shared__ int   ss[TILE];
  __shared__ float sxT[EMB_DIM][36];       // [d][s], pad 36 keeps b128 align
  __shared__ float sh[TILE][HIDDEN + 1];
  __shared__ float sw2[HIDDEN][OUT_DIM];

  if (t < TILE) ss[t] = perm[start + t];
  __syncthreads();
  if (ss[0] < 0) return;                   // pure-padding block (uniform exit)
  const int a = aspect[ss[0]];

  // stage x transposed (scalar reads ~38 KB/block; conflict-free LDS writes)
  for (int i = t; i < EMB_DIM * TILE; i += 256) {
    int d = i >> 5, s = i & 31;
    int smp = ss[s]; if (smp < 0) smp = ss[0];
    sxT[d][s] = x[(size_t)smp * EMB_DIM + d];
  }
  if (t < HIDDEN) {
#pragma unroll
    for (int k = 0; k < OUT_DIM; ++k)
      sw2[t][k] = W2[(size_t)a * HIDDEN * OUT_DIM + t * OUT_DIM + k];
  }
  __syncthreads();

  // layer 1: j = t
  float acc[TILE];
  const float bb = b1[a * HIDDEN + t];
#pragma unroll
  for (int s = 0; s < TILE; ++s) acc[s] = bb;
  const float* __restrict__ w1 = W1 + (size_t)a * EMB_DIM * HIDDEN + t;
#pragma unroll 2
  for (int d = 0; d < EMB_DIM; ++d) {
    float wv = w1[(size_t)d * HIDDEN];
    const float4* xrow = (const float4*)&sxT[d][0];
#pragma unroll
    for (int s4 = 0; s4 < 8; ++s4) {
      float4 xs = xrow[s4];
      acc[s4 * 4 + 0] = fmaf(xs.x, wv, acc[s4 * 4 + 0]);
      acc[s4 * 4 + 1] = fmaf(xs.y, wv, acc[s4 * 4 + 1]);
      acc[s4 * 4 + 2] = fmaf(xs.z, wv, acc[s4 * 4 + 2]);
      acc[s4 * 4 + 3] = fmaf(xs.w, wv, acc[s4 * 4 + 3]);
    }
  }
#pragma unroll
  for (int s = 0; s < TILE; ++s) sh[s][t] = fmaxf(acc[s], 0.f);
  __syncthreads();

  // layer 2: 96 threads, (s,k) each dot h[s][:] . W2[a][:][k]
  if (t < TILE * OUT_DIM) {
    int s = t / OUT_DIM, k = t % OUT_DIM;
    float o = b2[a * OUT_DIM + k];
    for (int jj = 0; jj < HIDDEN; ++jj)
      o = fmaf(sh[s][jj], sw2[jj][k], o);
    int smp = ss[s];
    if (smp >= 0) out[(size_t)smp * OUT_DIM + k] = o;
  }
}

// ---------------------------------------------------------------------------
extern "C" void kernel_launch(void* const* d_in, const int* in_sizes, int n_in,
                              void* d_out, int out_size, void* d_ws, size_t ws_size,
                              hipStream_t stream) {
  const int*   ids    = (const int*)d_in[0];   // [B, SEQ]
  const int*   aspect = (const int*)d_in[1];   // [B]
  const float* emb    = (const float*)d_in[2]; // [VOCAB, EMB_DIM]
  const float* W1     = (const float*)d_in[3];
  const float* b1     = (const float*)d_in[4];
  const float* W2     = (const float*)d_in[5];
  const float* b2     = (const float*)d_in[6];
  float*       out    = (float*)d_out;

  const int B = in_sizes[1];
  const int nblk  = (B + TILE - 1) / TILE + N_ASPECTS;  // padded upper bound
  const int nperm = nblk * TILE;

  // workspace layout
  float* x    = (float*)d_ws;                              // B*300 floats
  int*   meta = (int*)((char*)d_ws + (size_t)B * EMB_DIM * sizeof(float));
  int*   perm = meta + 64;

  pool_kernel<<<(B + 3) / 4, 256, 0, stream>>>(ids, emb, x, B);

  init_kernel<<<(nperm + 255) / 256, 256, 0, stream>>>(meta, perm, nperm);
  count_kernel<<<(B + 255) / 256, 256, 0, stream>>>(aspect, meta, B);
  prefix_kernel<<<1, 64, 0, stream>>>(meta);
  scatter_kernel<<<(B + 255) / 256, 256, 0, stream>>>(aspect, meta, perm, B);

  mlp_kernel<<<nblk, 256, 0, stream>>>(x, aspect, perm, W1, b1, W2, b2, out);
}

// Round 3
// 179.421 us; speedup vs baseline: 1.7228x; 1.7228x over previous
//
#include <hip/hip_runtime.h>

constexpr int EMB_DIM   = 300;
constexpr int HIDDEN    = 256;
constexpr int OUT_DIM   = 3;
constexpr int SEQ       = 128;
constexpr int N_ASPECTS = 8;
constexpr int TILE      = 32;    // samples per MLP block

// ---------------------------------------------------------------------------
// bf16 helpers (OCP bf16 = truncated fp32 with RNE)
// ---------------------------------------------------------------------------
__device__ __forceinline__ unsigned int bfbits(float f) {
  unsigned int u = __float_as_uint(f);
  return (u + 0x7fffu + ((u >> 16) & 1u)) >> 16;   // RNE; inputs are finite
}
__device__ __forceinline__ unsigned int pack2(float lo, float hi) {
  return bfbits(lo) | (bfbits(hi) << 16);
}
__device__ __forceinline__ float blo(unsigned int u) { return __uint_as_float(u << 16); }
__device__ __forceinline__ float bhi(unsigned int u) { return __uint_as_float(u & 0xffff0000u); }

// ---------------------------------------------------------------------------
// Convert fp32 table -> bf16 (streaming, 90 MB total). 8 floats/thread/iter.
// ---------------------------------------------------------------------------
__global__ __launch_bounds__(256) void convert_kernel(
    const float* __restrict__ emb, unsigned int* __restrict__ out, int n8) {
  int i = blockIdx.x * 256 + threadIdx.x;
  const int stride = gridDim.x * 256;
  for (; i < n8; i += stride) {
    const float4* p = (const float4*)emb + (size_t)i * 2;
    float4 a = p[0], b = p[1];
    uint4 o;
    o.x = pack2(a.x, a.y); o.y = pack2(a.z, a.w);
    o.z = pack2(b.x, b.y); o.w = pack2(b.z, b.w);
    ((uint4*)out)[i] = o;
  }
}

// ---------------------------------------------------------------------------
// Bucketing: ONE block, 1024 threads, deterministic counting sort by aspect.
// perm[pos] = sample index, buckets padded to TILE, padding = -1.
// ---------------------------------------------------------------------------
__global__ __launch_bounds__(1024) void bucket_kernel(
    const int* __restrict__ aspect, int B, int* __restrict__ perm, int nperm) {
  const int t = threadIdx.x;
  const int lane = t & 63, wave = t >> 6;          // 16 waves
  __shared__ int wcnt[16][N_ASPECTS];
  __shared__ int cur[16][N_ASPECTS];

  for (int i = t; i < nperm; i += 1024) perm[i] = -1;

  int my_a[8];
  int cnt[N_ASPECTS];
#pragma unroll
  for (int q = 0; q < N_ASPECTS; ++q) cnt[q] = 0;
#pragma unroll
  for (int k = 0; k < 8; ++k) {
    int s = t + k * 1024;
    int a = (s < B) ? aspect[s] : -1;
    my_a[k] = a;
#pragma unroll
    for (int q = 0; q < N_ASPECTS; ++q) cnt[q] += (a == q);
  }
#pragma unroll
  for (int q = 0; q < N_ASPECTS; ++q) {
    int c = cnt[q];
    for (int off = 32; off > 0; off >>= 1) c += __shfl_down(c, off);
    if (lane == 0) wcnt[wave][q] = c;
  }
  __syncthreads();
  if (t == 0) {
    int base = 0;
    for (int q = 0; q < N_ASPECTS; ++q) {
      int tot = 0;
      for (int w = 0; w < 16; ++w) { cur[w][q] = base + tot; tot += wcnt[w][q]; }
      base += ((tot + TILE - 1) / TILE) * TILE;
    }
  }
  __syncthreads();

#pragma unroll
  for (int k = 0; k < 8; ++k) {
    int a = my_a[k];
    int s = t + k * 1024;
#pragma unroll
    for (int q = 0; q < N_ASPECTS; ++q) {
      unsigned long long m = __ballot(a == q);
      if (a == q) {
        int rank = __popcll(m & ((1ull << lane) - 1ull));
        int pos = cur[wave][q] + rank;
        perm[pos] = s;
        if (rank == __popcll(m) - 1) cur[wave][q] = pos + 1;  // last lane bumps
      }
    }
  }
}

// ---------------------------------------------------------------------------
// Pool: one sample per wave, bf16 table, uint2 (=4 bf16) chunks.
// Lane l: chunk l (all lanes) + chunk 64+l (lanes 0..10) = 75 chunks = 300 d.
// ---------------------------------------------------------------------------
__global__ __launch_bounds__(256) void pool_kernel(
    const int* __restrict__ ids, const unsigned short* __restrict__ emb16,
    float* __restrict__ x, int B) {
  const int wave = threadIdx.x >> 6, lane = threadIdx.x & 63;
  const int b = blockIdx.x * 4 + wave;
  if (b >= B) return;

  __shared__ int sid[4][SEQ];
  sid[wave][lane]      = ids[(size_t)b * SEQ + lane];
  sid[wave][lane + 64] = ids[(size_t)b * SEQ + lane + 64];

  float a0 = 0.f, a1 = 0.f, a2 = 0.f, a3 = 0.f;
  float c0 = 0.f, c1 = 0.f, c2 = 0.f, c3 = 0.f;
#pragma unroll 4
  for (int s = 0; s < SEQ; ++s) {
    const uint2* __restrict__ r =
        (const uint2*)(emb16 + (size_t)sid[wave][s] * EMB_DIM);
    uint2 v = r[lane];
    a0 += blo(v.x); a1 += bhi(v.x); a2 += blo(v.y); a3 += bhi(v.y);
    if (lane < 11) {
      uint2 w = r[64 + lane];
      c0 += blo(w.x); c1 += bhi(w.x); c2 += blo(w.y); c3 += bhi(w.y);
    }
  }
  const float sc = 1.0f / (float)SEQ;
  float4* __restrict__ xr = (float4*)(x + (size_t)b * EMB_DIM);
  xr[lane] = make_float4(a0 * sc, a1 * sc, a2 * sc, a3 * sc);
  if (lane < 11)
    xr[64 + lane] = make_float4(c0 * sc, c1 * sc, c2 * sc, c3 * sc);
}

// ---------------------------------------------------------------------------
// Routed MLP, 32 same-aspect samples per block.
// Thread t -> cols {j0, j0+128} (j0 = t&127), sample half h = t>>7 (16 samples).
// Per d: 2 coalesced W1 loads + 4 LDS b128 broadcasts serve 32 FMAs.
// ---------------------------------------------------------------------------
__global__ __launch_bounds__(256) void mlp_kernel(
    const float* __restrict__ x, const int* __restrict__ aspect,
    const int* __restrict__ perm,
    const float* __restrict__ W1, const float* __restrict__ b1,
    const float* __restrict__ W2, const float* __restrict__ b2,
    float* __restrict__ out) {
  const int t = threadIdx.x;
  const int wave = t >> 6, lane = t & 63;
  const int start = blockIdx.x * TILE;

  __shared__ int   ss[TILE];
  __shared__ float sxT[EMB_DIM][36];       // [d][s]; 144 B rows keep b128 align
  __shared__ float sh[TILE][HIDDEN + 1];
  __shared__ float sw2[HIDDEN][OUT_DIM];

  if (t < TILE) ss[t] = perm[start + t];
  __syncthreads();
  if (ss[0] < 0) return;                   // pure-padding block (uniform exit)
  const int a = aspect[ss[0]];

  // stage x transposed: wave w -> samples w*8..w*8+7, float4-coalesced reads
  for (int s8 = 0; s8 < 8; ++s8) {
    const int s = wave * 8 + s8;
    int smp = ss[s]; if (smp < 0) smp = ss[0];
    const float4* __restrict__ xr = (const float4*)(x + (size_t)smp * EMB_DIM);
    float4 v = xr[lane];
    sxT[4 * lane + 0][s] = v.x; sxT[4 * lane + 1][s] = v.y;
    sxT[4 * lane + 2][s] = v.z; sxT[4 * lane + 3][s] = v.w;
    if (lane < 11) {
      float4 u = xr[64 + lane];
      const int d0 = 256 + 4 * lane;
      sxT[d0 + 0][s] = u.x; sxT[d0 + 1][s] = u.y;
      sxT[d0 + 2][s] = u.z; sxT[d0 + 3][s] = u.w;
    }
  }
  if (t < HIDDEN) {
#pragma unroll
    for (int k = 0; k < OUT_DIM; ++k)
      sw2[t][k] = W2[(size_t)a * HIDDEN * OUT_DIM + t * OUT_DIM + k];
  }
  __syncthreads();

  // layer 1: cols j0, j0+128 for 16 samples (half h)
  const int j0 = t & 127;
  const int h  = t >> 7;
  const int sbase = h * 16;
  float accA[16], accB[16];
  const float bbA = b1[a * HIDDEN + j0];
  const float bbB = b1[a * HIDDEN + j0 + 128];
#pragma unroll
  for (int s = 0; s < 16; ++s) { accA[s] = bbA; accB[s] = bbB; }
  const float* __restrict__ w1 = W1 + (size_t)a * EMB_DIM * HIDDEN;
#pragma unroll 2
  for (int d = 0; d < EMB_DIM; ++d) {
    const float wA = w1[(size_t)d * HIDDEN + j0];
    const float wB = w1[(size_t)d * HIDDEN + j0 + 128];
    const float4* xrow = (const float4*)&sxT[d][sbase];
#pragma unroll
    for (int s4 = 0; s4 < 4; ++s4) {
      float4 xs = xrow[s4];
      accA[s4 * 4 + 0] = fmaf(xs.x, wA, accA[s4 * 4 + 0]);
      accA[s4 * 4 + 1] = fmaf(xs.y, wA, accA[s4 * 4 + 1]);
      accA[s4 * 4 + 2] = fmaf(xs.z, wA, accA[s4 * 4 + 2]);
      accA[s4 * 4 + 3] = fmaf(xs.w, wA, accA[s4 * 4 + 3]);
      accB[s4 * 4 + 0] = fmaf(xs.x, wB, accB[s4 * 4 + 0]);
      accB[s4 * 4 + 1] = fmaf(xs.y, wB, accB[s4 * 4 + 1]);
      accB[s4 * 4 + 2] = fmaf(xs.z, wB, accB[s4 * 4 + 2]);
      accB[s4 * 4 + 3] = fmaf(xs.w, wB, accB[s4 * 4 + 3]);
    }
  }
#pragma unroll
  for (int s = 0; s < 16; ++s) {
    sh[sbase + s][j0]       = fmaxf(accA[s], 0.f);
    sh[sbase + s][j0 + 128] = fmaxf(accB[s], 0.f);
  }
  __syncthreads();

  // layer 2: 96 threads, (s,k) each dot h[s][:] . W2[a][:][k]
  if (t < TILE * OUT_DIM) {
    const int s = t / OUT_DIM, k = t % OUT_DIM;
    float o = b2[a * OUT_DIM + k];
    for (int jj = 0; jj < HIDDEN; ++jj)
      o = fmaf(sh[s][jj], sw2[jj][k], o);
    const int smp = ss[s];
    if (smp >= 0) out[(size_t)smp * OUT_DIM + k] = o;
  }
}

// ---------------------------------------------------------------------------
extern "C" void kernel_launch(void* const* d_in, const int* in_sizes, int n_in,
                              void* d_out, int out_size, void* d_ws, size_t ws_size,
                              hipStream_t stream) {
  const int*   ids    = (const int*)d_in[0];   // [B, SEQ]
  const int*   aspect = (const int*)d_in[1];   // [B]
  const float* emb    = (const float*)d_in[2]; // [VOCAB, EMB_DIM] fp32
  const float* W1     = (const float*)d_in[3];
  const float* b1     = (const float*)d_in[4];
  const float* W2     = (const float*)d_in[5];
  const float* b2     = (const float*)d_in[6];
  float*       out    = (float*)d_out;

  const int B     = in_sizes[1];
  const int nemb  = in_sizes[2];               // 15,000,000 (divisible by 8)
  const int nblk  = (B + TILE - 1) / TILE + N_ASPECTS;
  const int nperm = nblk * TILE;

  // workspace: [x: B*300 f32][perm: nperm i32][emb16: nemb bf16]
  float* x    = (float*)d_ws;
  int*   perm = (int*)((char*)d_ws + (size_t)B * EMB_DIM * sizeof(float));
  unsigned short* emb16 =
      (unsigned short*)((char*)perm + (((size_t)nperm * 4 + 15) & ~(size_t)15));

  bucket_kernel<<<1, 1024, 0, stream>>>(aspect, B, perm, nperm);
  convert_kernel<<<2048, 256, 0, stream>>>(emb, (unsigned int*)emb16, nemb / 8);
  pool_kernel<<<(B + 3) / 4, 256, 0, stream>>>(ids, emb16, x, B);
  mlp_kernel<<<nblk, 256, 0, stream>>>(x, aspect, perm, W1, b1, W2, b2, out);
}

// Round 4
// 166.876 us; speedup vs baseline: 1.8523x; 1.0752x over previous
//
#include <hip/hip_runtime.h>

constexpr int EMB_DIM   = 300;
constexpr int HIDDEN    = 256;
constexpr int OUT_DIM   = 3;
constexpr int SEQ       = 128;
constexpr int N_ASPECTS = 8;
constexpr int TILE      = 32;    // samples per MLP block (4 waves x 8 samples)

// ---------------------------------------------------------------------------
// bf16 helpers (RNE truncation of fp32)
// ---------------------------------------------------------------------------
__device__ __forceinline__ unsigned int bfbits(float f) {
  unsigned int u = __float_as_uint(f);
  return (u + 0x7fffu + ((u >> 16) & 1u)) >> 16;
}
__device__ __forceinline__ unsigned int pack2(float lo, float hi) {
  return bfbits(lo) | (bfbits(hi) << 16);
}
__device__ __forceinline__ float blo(unsigned int u) { return __uint_as_float(u << 16); }
__device__ __forceinline__ float bhi(unsigned int u) { return __uint_as_float(u & 0xffff0000u); }

// ---------------------------------------------------------------------------
// Fused prep: block 0 buckets samples by aspect (deterministic counting sort,
// buckets padded to TILE, padding = -1); blocks 1..N convert the fp32 table
// to bf16 (90 MB streaming). Bucket work hides under the HBM-bound convert.
// ---------------------------------------------------------------------------
__global__ __launch_bounds__(1024) void prep_kernel(
    const float* __restrict__ emb, unsigned int* __restrict__ emb16, int n8,
    const int* __restrict__ aspect, int B, int* __restrict__ perm, int nperm) {
  const int t = threadIdx.x;

  if (blockIdx.x != 0) {
    int i = (blockIdx.x - 1) * 1024 + t;
    const int stride = (gridDim.x - 1) * 1024;
    for (; i < n8; i += stride) {
      const float4* p = (const float4*)emb + (size_t)i * 2;
      float4 a = p[0], b = p[1];
      uint4 o;
      o.x = pack2(a.x, a.y); o.y = pack2(a.z, a.w);
      o.z = pack2(b.x, b.y); o.w = pack2(b.z, b.w);
      ((uint4*)emb16)[i] = o;
    }
    return;
  }

  // ---- block 0: bucketing (1024 threads = 16 waves) ----
  const int lane = t & 63, wave = t >> 6;
  __shared__ int wcnt[16][N_ASPECTS];
  __shared__ int cur[16][N_ASPECTS];

  for (int i = t; i < nperm; i += 1024) perm[i] = -1;

  int my_a[8];
  int cnt[N_ASPECTS];
#pragma unroll
  for (int q = 0; q < N_ASPECTS; ++q) cnt[q] = 0;
#pragma unroll
  for (int k = 0; k < 8; ++k) {
    int s = t + k * 1024;
    int a = (s < B) ? aspect[s] : -1;
    my_a[k] = a;
#pragma unroll
    for (int q = 0; q < N_ASPECTS; ++q) cnt[q] += (a == q);
  }
#pragma unroll
  for (int q = 0; q < N_ASPECTS; ++q) {
    int c = cnt[q];
    for (int off = 32; off > 0; off >>= 1) c += __shfl_down(c, off);
    if (lane == 0) wcnt[wave][q] = c;
  }
  __syncthreads();
  if (t == 0) {
    int base = 0;
    for (int q = 0; q < N_ASPECTS; ++q) {
      int tot = 0;
      for (int w = 0; w < 16; ++w) { cur[w][q] = base + tot; tot += wcnt[w][q]; }
      base += ((tot + TILE - 1) / TILE) * TILE;
    }
  }
  __syncthreads();

#pragma unroll
  for (int k = 0; k < 8; ++k) {
    int a = my_a[k];
    int s = t + k * 1024;
#pragma unroll
    for (int q = 0; q < N_ASPECTS; ++q) {
      unsigned long long m = __ballot(a == q);
      if (a == q) {
        int rank = __popcll(m & ((1ull << lane) - 1ull));
        int pos = cur[wave][q] + rank;
        perm[pos] = s;
        if (rank == __popcll(m) - 1) cur[wave][q] = pos + 1;
      }
    }
  }
}

// ---------------------------------------------------------------------------
// Pool: one sample per wave, bf16 table, uint2 (=4 bf16) chunks.
// Lane l: chunk l (all lanes) + chunk 64+l (lanes 0..10) = 75 chunks = 300 d.
// ---------------------------------------------------------------------------
__global__ __launch_bounds__(256) void pool_kernel(
    const int* __restrict__ ids, const unsigned short* __restrict__ emb16,
    float* __restrict__ x, int B) {
  const int wave = threadIdx.x >> 6, lane = threadIdx.x & 63;
  const int b = blockIdx.x * 4 + wave;
  if (b >= B) return;

  __shared__ int sid[4][SEQ];
  sid[wave][lane]      = ids[(size_t)b * SEQ + lane];
  sid[wave][lane + 64] = ids[(size_t)b * SEQ + lane + 64];

  float a0 = 0.f, a1 = 0.f, a2 = 0.f, a3 = 0.f;
  float c0 = 0.f, c1 = 0.f, c2 = 0.f, c3 = 0.f;
#pragma unroll 4
  for (int s = 0; s < SEQ; ++s) {
    const uint2* __restrict__ r =
        (const uint2*)(emb16 + (size_t)sid[wave][s] * EMB_DIM);
    uint2 v = r[lane];
    a0 += blo(v.x); a1 += bhi(v.x); a2 += blo(v.y); a3 += bhi(v.y);
    if (lane < 11) {
      uint2 w = r[64 + lane];
      c0 += blo(w.x); c1 += bhi(w.x); c2 += blo(w.y); c3 += bhi(w.y);
    }
  }
  const float sc = 1.0f / (float)SEQ;
  float4* __restrict__ xr = (float4*)(x + (size_t)b * EMB_DIM);
  xr[lane] = make_float4(a0 * sc, a1 * sc, a2 * sc, a3 * sc);
  if (lane < 11)
    xr[64 + lane] = make_float4(c0 * sc, c1 * sc, c2 * sc, c3 * sc);
}

// ---------------------------------------------------------------------------
// Routed MLP, no LDS in the hot loop. Wave owns 8 same-aspect samples; lane
// owns cols 4l..4l+3. Per d: 1 coalesced float4 W1 load (wave covers the
// full 1 KB row), broadcast x loads (L1-resident), 32 fp32 FMAs.
// Layer 2 in registers + 64-lane shuffle butterfly.
// ---------------------------------------------------------------------------
__global__ __launch_bounds__(256) void mlp_kernel(
    const float* __restrict__ x, const int* __restrict__ aspect,
    const int* __restrict__ perm,
    const float* __restrict__ W1, const float* __restrict__ b1,
    const float* __restrict__ W2, const float* __restrict__ b2,
    float* __restrict__ out) {
  const int t = threadIdx.x;
  const int wave = t >> 6, lane = t & 63;
  const int start = blockIdx.x * TILE;

  __shared__ int ss[TILE];
  if (t < TILE) ss[t] = perm[start + t];
  __syncthreads();
  const int smp0 = ss[0];
  if (smp0 < 0) return;                    // fully-padded block (uniform exit)
  const int a = aspect[smp0];

  // wave's 8 samples (wave-uniform scalars)
  int smp[8];
  const float* xrow[8];
#pragma unroll
  for (int s = 0; s < 8; ++s) {
    int m = __builtin_amdgcn_readfirstlane(ss[wave * 8 + s]);
    smp[s] = m;
    xrow[s] = x + (size_t)(m < 0 ? smp0 : m) * EMB_DIM;
  }

  // layer 1
  const float4* __restrict__ w1r =
      (const float4*)(W1 + (size_t)a * EMB_DIM * HIDDEN) + lane;
  const float4 bb = ((const float4*)(b1 + a * HIDDEN))[lane];
  float4 acc[8];
#pragma unroll
  for (int s = 0; s < 8; ++s) acc[s] = bb;

  for (int d = 0; d < EMB_DIM; d += 4) {
    float4 xv[8];
#pragma unroll
    for (int s = 0; s < 8; ++s) xv[s] = *(const float4*)(xrow[s] + d);
#pragma unroll
    for (int dd = 0; dd < 4; ++dd) {
      const float4 w = w1r[(size_t)(d + dd) * (HIDDEN / 4)];
#pragma unroll
      for (int s = 0; s < 8; ++s) {
        const float xs = dd == 0 ? xv[s].x : dd == 1 ? xv[s].y
                        : dd == 2 ? xv[s].z : xv[s].w;
        acc[s].x = fmaf(xs, w.x, acc[s].x);
        acc[s].y = fmaf(xs, w.y, acc[s].y);
        acc[s].z = fmaf(xs, w.z, acc[s].z);
        acc[s].w = fmaf(xs, w.w, acc[s].w);
      }
    }
  }

  // layer 2: cols j = 4*lane..4*lane+3, k = 0..2; 12 consecutive W2 floats
  const float4* __restrict__ w2p =
      (const float4*)(W2 + (size_t)a * HIDDEN * OUT_DIM + lane * 12);
  const float4 w2a = w2p[0];   // j0k0 j0k1 j0k2 j1k0
  const float4 w2b = w2p[1];   // j1k1 j1k2 j2k0 j2k1
  const float4 w2c = w2p[2];   // j2k2 j3k0 j3k1 j3k2

  float p[8][OUT_DIM];
#pragma unroll
  for (int s = 0; s < 8; ++s) {
    const float h0 = fmaxf(acc[s].x, 0.f), h1 = fmaxf(acc[s].y, 0.f);
    const float h2 = fmaxf(acc[s].z, 0.f), h3 = fmaxf(acc[s].w, 0.f);
    p[s][0] = fmaf(h0, w2a.x, fmaf(h1, w2a.w, fmaf(h2, w2b.z, h3 * w2c.y)));
    p[s][1] = fmaf(h0, w2a.y, fmaf(h1, w2b.x, fmaf(h2, w2b.w, h3 * w2c.z)));
    p[s][2] = fmaf(h0, w2a.z, fmaf(h1, w2b.y, fmaf(h2, w2c.x, h3 * w2c.w)));
  }
#pragma unroll
  for (int off = 32; off > 0; off >>= 1)
#pragma unroll
    for (int s = 0; s < 8; ++s) {
      p[s][0] += __shfl_down(p[s][0], off);
      p[s][1] += __shfl_down(p[s][1], off);
      p[s][2] += __shfl_down(p[s][2], off);
    }

  if (lane == 0) {
    const float g0 = b2[a * OUT_DIM + 0];
    const float g1 = b2[a * OUT_DIM + 1];
    const float g2 = b2[a * OUT_DIM + 2];
#pragma unroll
    for (int s = 0; s < 8; ++s)
      if (smp[s] >= 0) {
        float* o = out + (size_t)smp[s] * OUT_DIM;
        o[0] = p[s][0] + g0;
        o[1] = p[s][1] + g1;
        o[2] = p[s][2] + g2;
      }
  }
}

// ---------------------------------------------------------------------------
extern "C" void kernel_launch(void* const* d_in, const int* in_sizes, int n_in,
                              void* d_out, int out_size, void* d_ws, size_t ws_size,
                              hipStream_t stream) {
  const int*   ids    = (const int*)d_in[0];   // [B, SEQ]
  const int*   aspect = (const int*)d_in[1];   // [B]
  const float* emb    = (const float*)d_in[2]; // [VOCAB, EMB_DIM] fp32
  const float* W1     = (const float*)d_in[3];
  const float* b1     = (const float*)d_in[4];
  const float* W2     = (const float*)d_in[5];
  const float* b2     = (const float*)d_in[6];
  float*       out    = (float*)d_out;

  const int B     = in_sizes[1];
  const int nemb  = in_sizes[2];               // 15,000,000 (divisible by 8)
  const int nblk  = (B + TILE - 1) / TILE + N_ASPECTS;
  const int nperm = nblk * TILE;

  // workspace: [x: B*300 f32][perm: nperm i32][emb16: nemb bf16]
  float* x    = (float*)d_ws;
  int*   perm = (int*)((char*)d_ws + (size_t)B * EMB_DIM * sizeof(float));
  unsigned short* emb16 =
      (unsigned short*)((char*)perm + (((size_t)nperm * 4 + 15) & ~(size_t)15));

  prep_kernel<<<513, 1024, 0, stream>>>(emb, (unsigned int*)emb16, nemb / 8,
                                        aspect, B, perm, nperm);
  pool_kernel<<<(B + 3) / 4, 256, 0, stream>>>(ids, emb16, x, B);
  mlp_kernel<<<nblk, 256, 0, stream>>>(x, aspect, perm, W1, b1, W2, b2, out);
}

// Round 5
// 143.382 us; speedup vs baseline: 2.1558x; 1.1639x over previous
//
#include <hip/hip_runtime.h>

constexpr int EMB_DIM   = 300;
constexpr int HIDDEN    = 256;
constexpr int OUT_DIM   = 3;
constexpr int SEQ       = 128;
constexpr int N_ASPECTS = 8;
constexpr int TILE      = 32;    // bucket padding granularity
constexpr int MTILE     = 16;    // samples per MLP block (2 groups x 8)

// ---------------------------------------------------------------------------
// bf16 helpers (RNE)
// ---------------------------------------------------------------------------
__device__ __forceinline__ unsigned int bfbits(float f) {
  unsigned int u = __float_as_uint(f);
  return (u + 0x7fffu + ((u >> 16) & 1u)) >> 16;
}
__device__ __forceinline__ unsigned int pack2(float lo, float hi) {
  return bfbits(lo) | (bfbits(hi) << 16);
}
__device__ __forceinline__ float blo(unsigned int u) { return __uint_as_float(u << 16); }
__device__ __forceinline__ float bhi(unsigned int u) { return __uint_as_float(u & 0xffff0000u); }

// ---------------------------------------------------------------------------
// Fused prep: block 0 = deterministic counting-sort bucketing (pad to TILE,
// -1 = padding); blocks 1..N = fp32->bf16 table conversion (90 MB stream).
// ---------------------------------------------------------------------------
__global__ __launch_bounds__(1024) void prep_kernel(
    const float* __restrict__ emb, unsigned int* __restrict__ emb16, int n8,
    const int* __restrict__ aspect, int B, int* __restrict__ perm, int nperm) {
  const int t = threadIdx.x;

  if (blockIdx.x != 0) {
    int i = (blockIdx.x - 1) * 1024 + t;
    const int stride = (gridDim.x - 1) * 1024;
    for (; i < n8; i += stride) {
      const float4* p = (const float4*)emb + (size_t)i * 2;
      float4 a = p[0], b = p[1];
      uint4 o;
      o.x = pack2(a.x, a.y); o.y = pack2(a.z, a.w);
      o.z = pack2(b.x, b.y); o.w = pack2(b.z, b.w);
      ((uint4*)emb16)[i] = o;
    }
    return;
  }

  const int lane = t & 63, wave = t >> 6;          // 16 waves
  __shared__ int wcnt[16][N_ASPECTS];
  __shared__ int cur[16][N_ASPECTS];

  for (int i = t; i < nperm; i += 1024) perm[i] = -1;

  int my_a[8];
  int cnt[N_ASPECTS];
#pragma unroll
  for (int q = 0; q < N_ASPECTS; ++q) cnt[q] = 0;
#pragma unroll
  for (int k = 0; k < 8; ++k) {
    int s = t + k * 1024;
    int a = (s < B) ? aspect[s] : -1;
    my_a[k] = a;
#pragma unroll
    for (int q = 0; q < N_ASPECTS; ++q) cnt[q] += (a == q);
  }
#pragma unroll
  for (int q = 0; q < N_ASPECTS; ++q) {
    int c = cnt[q];
    for (int off = 32; off > 0; off >>= 1) c += __shfl_down(c, off);
    if (lane == 0) wcnt[wave][q] = c;
  }
  __syncthreads();
  if (t == 0) {
    int base = 0;
    for (int q = 0; q < N_ASPECTS; ++q) {
      int tot = 0;
      for (int w = 0; w < 16; ++w) { cur[w][q] = base + tot; tot += wcnt[w][q]; }
      base += ((tot + TILE - 1) / TILE) * TILE;
    }
  }
  __syncthreads();

#pragma unroll
  for (int k = 0; k < 8; ++k) {
    int a = my_a[k];
    int s = t + k * 1024;
#pragma unroll
    for (int q = 0; q < N_ASPECTS; ++q) {
      unsigned long long m = __ballot(a == q);
      if (a == q) {
        int rank = __popcll(m & ((1ull << lane) - 1ull));
        int pos = cur[wave][q] + rank;
        perm[pos] = s;
        if (rank == __popcll(m) - 1) cur[wave][q] = pos + 1;
      }
    }
  }
}

// ---------------------------------------------------------------------------
// Pool: one sample per wave. NEW: bitonic-sort the 128 ids (regs + shfl) so
// all co-resident waves sweep the vocab in ascending order -> the hot window
// stays L2-resident (convoy is self-synchronizing: stragglers hit L2).
// A compare-exchange always preserves the multiset, so even a sort bug could
// only cost locality, never correctness.
// ---------------------------------------------------------------------------
__global__ __launch_bounds__(256) void pool_kernel(
    const int* __restrict__ ids, const unsigned short* __restrict__ emb16,
    float* __restrict__ x, int B) {
  const int wave = threadIdx.x >> 6, lane = threadIdx.x & 63;
  const int b = blockIdx.x * 4 + wave;
  if (b >= B) return;

  // load 2 ids per lane: element i0=lane, i1=lane+64
  int r0 = ids[(size_t)b * SEQ + lane];
  int r1 = ids[(size_t)b * SEQ + lane + 64];

  // bitonic sort of 128 elements across 64 lanes x 2 regs
#pragma unroll
  for (int k = 2; k <= 128; k <<= 1) {
#pragma unroll
    for (int j = k >> 1; j >= 1; j >>= 1) {
      if (j == 64) {                       // only k=128: pair within lane
        int lo = min(r0, r1), hi = max(r0, r1);
        r0 = lo; r1 = hi;
      } else {
        const bool up0 = ((lane & k) == 0);
        const bool up1 = (((lane + 64) & k) == 0);
        const bool side = ((lane & j) == 0);
        int o0 = __shfl_xor(r0, j);
        int o1 = __shfl_xor(r1, j);
        r0 = (side == up0) ? min(r0, o0) : max(r0, o0);
        r1 = (side == up1) ? min(r1, o1) : max(r1, o1);
      }
    }
  }

  __shared__ int sid[4][SEQ];
  sid[wave][lane]      = r0;
  sid[wave][lane + 64] = r1;
  __syncthreads();

  float a0 = 0.f, a1 = 0.f, a2 = 0.f, a3 = 0.f;
  float c0 = 0.f, c1 = 0.f, c2 = 0.f, c3 = 0.f;
#pragma unroll 4
  for (int s = 0; s < SEQ; ++s) {
    const uint2* __restrict__ r =
        (const uint2*)(emb16 + (size_t)sid[wave][s] * EMB_DIM);
    uint2 v = r[lane];
    a0 += blo(v.x); a1 += bhi(v.x); a2 += blo(v.y); a3 += bhi(v.y);
    if (lane < 11) {
      uint2 w = r[64 + lane];
      c0 += blo(w.x); c1 += bhi(w.x); c2 += blo(w.y); c3 += bhi(w.y);
    }
  }
  const float sc = 1.0f / (float)SEQ;
  float4* __restrict__ xr = (float4*)(x + (size_t)b * EMB_DIM);
  xr[lane] = make_float4(a0 * sc, a1 * sc, a2 * sc, a3 * sc);
  if (lane < 11)
    xr[64 + lane] = make_float4(c0 * sc, c1 * sc, c2 * sc, c3 * sc);
}

// ---------------------------------------------------------------------------
// Routed MLP with split-K: block = 256 thr = 4 waves = 2 groups x 2 K-halves.
// Group owns 8 same-aspect samples; wave kw does d-range [0,160) or [160,300),
// partials exchanged via LDS; wave kw finishes samples [4kw,4kw+4).
// 2048 waves total -> 2 waves/SIMD (was 1) to hide load latency.
// ---------------------------------------------------------------------------
__global__ __launch_bounds__(256) void mlp_kernel(
    const float* __restrict__ x, const int* __restrict__ aspect,
    const int* __restrict__ perm,
    const float* __restrict__ W1, const float* __restrict__ b1,
    const float* __restrict__ W2, const float* __restrict__ b2,
    float* __restrict__ out) {
  const int t = threadIdx.x;
  const int wave = t >> 6, lane = t & 63;
  const int g = wave >> 1;                 // sample group 0/1
  const int kw = wave & 1;                 // K-half
  const int start = blockIdx.x * MTILE;

  __shared__ int ss[MTILE];
  __shared__ float xch[2][8][64][4];       // partial exchange, 16 KB

  if (t < MTILE) ss[t] = perm[start + t];
  __syncthreads();
  const int s0 = ss[0];
  if (s0 < 0) return;                      // fully-padded block (uniform exit)
  const int a = aspect[s0];

  int smp[8];
  const float* xrow[8];
#pragma unroll
  for (int s = 0; s < 8; ++s) {
    int m = __builtin_amdgcn_readfirstlane(ss[g * 8 + s]);
    smp[s] = m;
    xrow[s] = x + (size_t)(m < 0 ? s0 : m) * EMB_DIM;
  }

  // layer 1 over this wave's K-range
  const float4* __restrict__ w1r =
      (const float4*)(W1 + (size_t)a * EMB_DIM * HIDDEN) + lane;
  float4 acc[8];
  if (kw == 0) {
    const float4 bb = ((const float4*)(b1 + a * HIDDEN))[lane];
#pragma unroll
    for (int s = 0; s < 8; ++s) acc[s] = bb;
  } else {
#pragma unroll
    for (int s = 0; s < 8; ++s) acc[s] = make_float4(0.f, 0.f, 0.f, 0.f);
  }
  const int d0 = kw ? 160 : 0;
  const int d1 = kw ? EMB_DIM : 160;
  for (int d = d0; d < d1; d += 4) {
    float4 xv[8];
#pragma unroll
    for (int s = 0; s < 8; ++s) xv[s] = *(const float4*)(xrow[s] + d);
#pragma unroll
    for (int dd = 0; dd < 4; ++dd) {
      const float4 w = w1r[(size_t)(d + dd) * (HIDDEN / 4)];
#pragma unroll
      for (int s = 0; s < 8; ++s) {
        const float xs = dd == 0 ? xv[s].x : dd == 1 ? xv[s].y
                        : dd == 2 ? xv[s].z : xv[s].w;
        acc[s].x = fmaf(xs, w.x, acc[s].x);
        acc[s].y = fmaf(xs, w.y, acc[s].y);
        acc[s].z = fmaf(xs, w.z, acc[s].z);
        acc[s].w = fmaf(xs, w.w, acc[s].w);
      }
    }
  }

  // exchange partials for the other wave's samples
  const int oth = 4 * (1 - kw);
#pragma unroll
  for (int i = 0; i < 4; ++i)
    *(float4*)&xch[g][oth + i][lane][0] = acc[oth + i];
  __syncthreads();

  // finish samples [4kw, 4kw+4)
  const float4* __restrict__ w2p =
      (const float4*)(W2 + (size_t)a * HIDDEN * OUT_DIM + lane * 12);
  const float4 w2a = w2p[0];   // j0k0 j0k1 j0k2 j1k0
  const float4 w2b = w2p[1];   // j1k1 j1k2 j2k0 j2k1
  const float4 w2c = w2p[2];   // j2k2 j3k0 j3k1 j3k2

  const int mys = 4 * kw;
  float p[4][OUT_DIM];
#pragma unroll
  for (int i = 0; i < 4; ++i) {
    const int s = mys + i;
    const float4 pr = *(const float4*)&xch[g][s][lane][0];
    const float h0 = fmaxf(acc[s].x + pr.x, 0.f);
    const float h1 = fmaxf(acc[s].y + pr.y, 0.f);
    const float h2 = fmaxf(acc[s].z + pr.z, 0.f);
    const float h3 = fmaxf(acc[s].w + pr.w, 0.f);
    p[i][0] = fmaf(h0, w2a.x, fmaf(h1, w2a.w, fmaf(h2, w2b.z, h3 * w2c.y)));
    p[i][1] = fmaf(h0, w2a.y, fmaf(h1, w2b.x, fmaf(h2, w2b.w, h3 * w2c.z)));
    p[i][2] = fmaf(h0, w2a.z, fmaf(h1, w2b.y, fmaf(h2, w2c.x, h3 * w2c.w)));
  }
#pragma unroll
  for (int off = 32; off > 0; off >>= 1)
#pragma unroll
    for (int i = 0; i < 4; ++i) {
      p[i][0] += __shfl_down(p[i][0], off);
      p[i][1] += __shfl_down(p[i][1], off);
      p[i][2] += __shfl_down(p[i][2], off);
    }

  if (lane == 0) {
    const float g0 = b2[a * OUT_DIM + 0];
    const float g1 = b2[a * OUT_DIM + 1];
    const float g2 = b2[a * OUT_DIM + 2];
#pragma unroll
    for (int i = 0; i < 4; ++i) {
      const int m = smp[mys + i];
      if (m >= 0) {
        float* o = out + (size_t)m * OUT_DIM;
        o[0] = p[i][0] + g0;
        o[1] = p[i][1] + g1;
        o[2] = p[i][2] + g2;
      }
    }
  }
}

// ---------------------------------------------------------------------------
extern "C" void kernel_launch(void* const* d_in, const int* in_sizes, int n_in,
                              void* d_out, int out_size, void* d_ws, size_t ws_size,
                              hipStream_t stream) {
  const int*   ids    = (const int*)d_in[0];
  const int*   aspect = (const int*)d_in[1];
  const float* emb    = (const float*)d_in[2];
  const float* W1     = (const float*)d_in[3];
  const float* b1     = (const float*)d_in[4];
  const float* W2     = (const float*)d_in[5];
  const float* b2     = (const float*)d_in[6];
  float*       out    = (float*)d_out;

  const int B     = in_sizes[1];
  const int nemb  = in_sizes[2];
  const int nblk  = (B + TILE - 1) / TILE + N_ASPECTS;
  const int nperm = nblk * TILE;           // multiple of 32 (and of MTILE)

  float* x    = (float*)d_ws;
  int*   perm = (int*)((char*)d_ws + (size_t)B * EMB_DIM * sizeof(float));
  unsigned short* emb16 =
      (unsigned short*)((char*)perm + (((size_t)nperm * 4 + 15) & ~(size_t)15));

  prep_kernel<<<513, 1024, 0, stream>>>(emb, (unsigned int*)emb16, nemb / 8,
                                        aspect, B, perm, nperm);
  pool_kernel<<<(B + 3) / 4, 256, 0, stream>>>(ids, emb16, x, B);
  mlp_kernel<<<nperm / MTILE, 256, 0, stream>>>(x, aspect, perm, W1, b1, W2, b2, out);
}

// Round 6
// 131.371 us; speedup vs baseline: 2.3529x; 1.0914x over previous
//
#include <hip/hip_runtime.h>

constexpr int EMB_DIM   = 300;
constexpr int HIDDEN    = 256;
constexpr int OUT_DIM   = 3;
constexpr int SEQ       = 128;
constexpr int N_ASPECTS = 8;
constexpr int TILE      = 32;    // bucket padding granularity
constexpr int MTILE     = 16;    // samples per MLP block (2 groups x 8)

// ---------------------------------------------------------------------------
// bf16 helpers (RNE)
// ---------------------------------------------------------------------------
__device__ __forceinline__ unsigned int bfbits(float f) {
  unsigned int u = __float_as_uint(f);
  return (u + 0x7fffu + ((u >> 16) & 1u)) >> 16;
}
__device__ __forceinline__ unsigned int pack2(float lo, float hi) {
  return bfbits(lo) | (bfbits(hi) << 16);
}
__device__ __forceinline__ float blo(unsigned int u) { return __uint_as_float(u << 16); }
__device__ __forceinline__ float bhi(unsigned int u) { return __uint_as_float(u & 0xffff0000u); }

// ---------------------------------------------------------------------------
// Fused prep: block 0 = deterministic counting-sort bucketing (pad to TILE,
// -1 = padding); blocks 1..N = fp32->bf16 table conversion (90 MB stream).
// ---------------------------------------------------------------------------
__global__ __launch_bounds__(1024) void prep_kernel(
    const float* __restrict__ emb, unsigned int* __restrict__ emb16, int n8,
    const int* __restrict__ aspect, int B, int* __restrict__ perm, int nperm) {
  const int t = threadIdx.x;

  if (blockIdx.x != 0) {
    int i = (blockIdx.x - 1) * 1024 + t;
    const int stride = (gridDim.x - 1) * 1024;
    for (; i < n8; i += stride) {
      const float4* p = (const float4*)emb + (size_t)i * 2;
      float4 a = p[0], b = p[1];
      uint4 o;
      o.x = pack2(a.x, a.y); o.y = pack2(a.z, a.w);
      o.z = pack2(b.x, b.y); o.w = pack2(b.z, b.w);
      ((uint4*)emb16)[i] = o;
    }
    return;
  }

  const int lane = t & 63, wave = t >> 6;          // 16 waves
  __shared__ int wcnt[16][N_ASPECTS];
  __shared__ int cur[16][N_ASPECTS];

  for (int i = t; i < nperm; i += 1024) perm[i] = -1;

  int my_a[8];
  int cnt[N_ASPECTS];
#pragma unroll
  for (int q = 0; q < N_ASPECTS; ++q) cnt[q] = 0;
#pragma unroll
  for (int k = 0; k < 8; ++k) {
    int s = t + k * 1024;
    int a = (s < B) ? aspect[s] : -1;
    my_a[k] = a;
#pragma unroll
    for (int q = 0; q < N_ASPECTS; ++q) cnt[q] += (a == q);
  }
#pragma unroll
  for (int q = 0; q < N_ASPECTS; ++q) {
    int c = cnt[q];
    for (int off = 32; off > 0; off >>= 1) c += __shfl_down(c, off);
    if (lane == 0) wcnt[wave][q] = c;
  }
  __syncthreads();
  if (t == 0) {
    int base = 0;
    for (int q = 0; q < N_ASPECTS; ++q) {
      int tot = 0;
      for (int w = 0; w < 16; ++w) { cur[w][q] = base + tot; tot += wcnt[w][q]; }
      base += ((tot + TILE - 1) / TILE) * TILE;
    }
  }
  __syncthreads();

#pragma unroll
  for (int k = 0; k < 8; ++k) {
    int a = my_a[k];
    int s = t + k * 1024;
#pragma unroll
    for (int q = 0; q < N_ASPECTS; ++q) {
      unsigned long long m = __ballot(a == q);
      if (a == q) {
        int rank = __popcll(m & ((1ull << lane) - 1ull));
        int pos = cur[wave][q] + rank;
        perm[pos] = s;
        if (rank == __popcll(m) - 1) cur[wave][q] = pos + 1;
      }
    }
  }
}

// ---------------------------------------------------------------------------
// Pool: one sample per wave; bitonic-sort the 128 ids (regs + shfl) so all
// co-resident waves sweep the vocab in ascending order (L2-resident window;
// convoy self-synchronizes). Sort bugs could only cost locality, never
// correctness (compare-exchange preserves the multiset).
// ---------------------------------------------------------------------------
__global__ __launch_bounds__(256) void pool_kernel(
    const int* __restrict__ ids, const unsigned short* __restrict__ emb16,
    float* __restrict__ x, int B) {
  const int wave = threadIdx.x >> 6, lane = threadIdx.x & 63;
  const int b = blockIdx.x * 4 + wave;
  if (b >= B) return;

  int r0 = ids[(size_t)b * SEQ + lane];
  int r1 = ids[(size_t)b * SEQ + lane + 64];

#pragma unroll
  for (int k = 2; k <= 128; k <<= 1) {
#pragma unroll
    for (int j = k >> 1; j >= 1; j >>= 1) {
      if (j == 64) {
        int lo = min(r0, r1), hi = max(r0, r1);
        r0 = lo; r1 = hi;
      } else {
        const bool up0 = ((lane & k) == 0);
        const bool up1 = (((lane + 64) & k) == 0);
        const bool side = ((lane & j) == 0);
        int o0 = __shfl_xor(r0, j);
        int o1 = __shfl_xor(r1, j);
        r0 = (side == up0) ? min(r0, o0) : max(r0, o0);
        r1 = (side == up1) ? min(r1, o1) : max(r1, o1);
      }
    }
  }

  __shared__ int sid[4][SEQ];
  sid[wave][lane]      = r0;
  sid[wave][lane + 64] = r1;
  __syncthreads();

  float a0 = 0.f, a1 = 0.f, a2 = 0.f, a3 = 0.f;
  float c0 = 0.f, c1 = 0.f, c2 = 0.f, c3 = 0.f;
#pragma unroll 4
  for (int s = 0; s < SEQ; ++s) {
    const uint2* __restrict__ r =
        (const uint2*)(emb16 + (size_t)sid[wave][s] * EMB_DIM);
    uint2 v = r[lane];
    a0 += blo(v.x); a1 += bhi(v.x); a2 += blo(v.y); a3 += bhi(v.y);
    if (lane < 11) {
      uint2 w = r[64 + lane];
      c0 += blo(w.x); c1 += bhi(w.x); c2 += blo(w.y); c3 += bhi(w.y);
    }
  }
  const float sc = 1.0f / (float)SEQ;
  float4* __restrict__ xr = (float4*)(x + (size_t)b * EMB_DIM);
  xr[lane] = make_float4(a0 * sc, a1 * sc, a2 * sc, a3 * sc);
  if (lane < 11)
    xr[64 + lane] = make_float4(c0 * sc, c1 * sc, c2 * sc, c3 * sc);
}

// ---------------------------------------------------------------------------
// Routed MLP, split-K: 4 waves = 2 groups x 2 K-halves. ALL register-array
// indices are compile-time constants (rule #20: runtime-indexed reg arrays
// demote to scratch -- R5's 33MB WRITE_SIZE bug). kw-dependent accesses are
// handled by wave-uniform if/else with static indices; __syncthreads sits
// OUTSIDE the branches so every wave reaches it.
// ---------------------------------------------------------------------------
__global__ __launch_bounds__(256) void mlp_kernel(
    const float* __restrict__ x, const int* __restrict__ aspect,
    const int* __restrict__ perm,
    const float* __restrict__ W1, const float* __restrict__ b1,
    const float* __restrict__ W2, const float* __restrict__ b2,
    float* __restrict__ out) {
  const int t = threadIdx.x;
  const int wave = t >> 6, lane = t & 63;
  const int g = wave >> 1;                 // sample group 0/1
  const int kw = wave & 1;                 // K-half
  const int start = blockIdx.x * MTILE;

  __shared__ int ss[MTILE];
  __shared__ float xch[2][8][64][4];       // partner-half partials, 16 KB

  if (t < MTILE) ss[t] = perm[start + t];
  __syncthreads();
  const int s0 = ss[0];
  if (s0 < 0) return;                      // fully-padded block (uniform exit)
  const int a = aspect[s0];

  int smp[8];
  const float* xrow[8];
#pragma unroll
  for (int s = 0; s < 8; ++s) {
    int m = __builtin_amdgcn_readfirstlane(ss[g * 8 + s]);
    smp[s] = m;
    xrow[s] = x + (size_t)(m < 0 ? s0 : m) * EMB_DIM;
  }

  // layer 1 over this wave's K-range
  const float4* __restrict__ w1r =
      (const float4*)(W1 + (size_t)a * EMB_DIM * HIDDEN) + lane;
  float4 acc[8];
  if (kw == 0) {
    const float4 bb = ((const float4*)(b1 + a * HIDDEN))[lane];
#pragma unroll
    for (int s = 0; s < 8; ++s) acc[s] = bb;
  } else {
#pragma unroll
    for (int s = 0; s < 8; ++s) acc[s] = make_float4(0.f, 0.f, 0.f, 0.f);
  }
  const int d0 = kw ? 160 : 0;
  const int d1 = kw ? EMB_DIM : 160;
  for (int d = d0; d < d1; d += 4) {
    float4 xv[8];
#pragma unroll
    for (int s = 0; s < 8; ++s) xv[s] = *(const float4*)(xrow[s] + d);
#pragma unroll
    for (int dd = 0; dd < 4; ++dd) {
      const float4 w = w1r[(size_t)(d + dd) * (HIDDEN / 4)];
#pragma unroll
      for (int s = 0; s < 8; ++s) {
        const float xs = dd == 0 ? xv[s].x : dd == 1 ? xv[s].y
                        : dd == 2 ? xv[s].z : xv[s].w;
        acc[s].x = fmaf(xs, w.x, acc[s].x);
        acc[s].y = fmaf(xs, w.y, acc[s].y);
        acc[s].z = fmaf(xs, w.z, acc[s].z);
        acc[s].w = fmaf(xs, w.w, acc[s].w);
      }
    }
  }

  // hand the partner wave its half's partials (static acc indices per branch)
  if (kw == 0) {
#pragma unroll
    for (int i = 0; i < 4; ++i)
      *(float4*)&xch[g][4 + i][lane][0] = acc[4 + i];
  } else {
#pragma unroll
    for (int i = 0; i < 4; ++i)
      *(float4*)&xch[g][i][lane][0] = acc[i];
  }
  __syncthreads();

  // finish my 4 samples: own = acc[static], partner = LDS (runtime LDS ok)
  const float4* __restrict__ w2p =
      (const float4*)(W2 + (size_t)a * HIDDEN * OUT_DIM + lane * 12);
  const float4 w2a = w2p[0];   // j0k0 j0k1 j0k2 j1k0
  const float4 w2b = w2p[1];   // j1k1 j1k2 j2k0 j2k1
  const float4 w2c = w2p[2];   // j2k2 j3k0 j3k1 j3k2

  float4 own[4];
  int ms[4];
  if (kw == 0) {
    own[0] = acc[0]; own[1] = acc[1]; own[2] = acc[2]; own[3] = acc[3];
    ms[0] = smp[0]; ms[1] = smp[1]; ms[2] = smp[2]; ms[3] = smp[3];
  } else {
    own[0] = acc[4]; own[1] = acc[5]; own[2] = acc[6]; own[3] = acc[7];
    ms[0] = smp[4]; ms[1] = smp[5]; ms[2] = smp[6]; ms[3] = smp[7];
  }
  const int mys = 4 * kw;                  // LDS base (runtime ok)

  float p[4][OUT_DIM];
#pragma unroll
  for (int i = 0; i < 4; ++i) {
    const float4 pr = *(const float4*)&xch[g][mys + i][lane][0];
    const float h0 = fmaxf(own[i].x + pr.x, 0.f);
    const float h1 = fmaxf(own[i].y + pr.y, 0.f);
    const float h2 = fmaxf(own[i].z + pr.z, 0.f);
    const float h3 = fmaxf(own[i].w + pr.w, 0.f);
    p[i][0] = fmaf(h0, w2a.x, fmaf(h1, w2a.w, fmaf(h2, w2b.z, h3 * w2c.y)));
    p[i][1] = fmaf(h0, w2a.y, fmaf(h1, w2b.x, fmaf(h2, w2b.w, h3 * w2c.z)));
    p[i][2] = fmaf(h0, w2a.z, fmaf(h1, w2b.y, fmaf(h2, w2c.x, h3 * w2c.w)));
  }
#pragma unroll
  for (int off = 32; off > 0; off >>= 1)
#pragma unroll
    for (int i = 0; i < 4; ++i) {
      p[i][0] += __shfl_down(p[i][0], off);
      p[i][1] += __shfl_down(p[i][1], off);
      p[i][2] += __shfl_down(p[i][2], off);
    }

  if (lane == 0) {
    const float g0 = b2[a * OUT_DIM + 0];
    const float g1 = b2[a * OUT_DIM + 1];
    const float g2 = b2[a * OUT_DIM + 2];
#pragma unroll
    for (int i = 0; i < 4; ++i) {
      if (ms[i] >= 0) {
        float* o = out + (size_t)ms[i] * OUT_DIM;
        o[0] = p[i][0] + g0;
        o[1] = p[i][1] + g1;
        o[2] = p[i][2] + g2;
      }
    }
  }
}

// ---------------------------------------------------------------------------
extern "C" void kernel_launch(void* const* d_in, const int* in_sizes, int n_in,
                              void* d_out, int out_size, void* d_ws, size_t ws_size,
                              hipStream_t stream) {
  const int*   ids    = (const int*)d_in[0];
  const int*   aspect = (const int*)d_in[1];
  const float* emb    = (const float*)d_in[2];
  const float* W1     = (const float*)d_in[3];
  const float* b1     = (const float*)d_in[4];
  const float* W2     = (const float*)d_in[5];
  const float* b2     = (const float*)d_in[6];
  float*       out    = (float*)d_out;

  const int B     = in_sizes[1];
  const int nemb  = in_sizes[2];
  const int nblk  = (B + TILE - 1) / TILE + N_ASPECTS;
  const int nperm = nblk * TILE;           // multiple of 32 (and of MTILE)

  float* x    = (float*)d_ws;
  int*   perm = (int*)((char*)d_ws + (size_t)B * EMB_DIM * sizeof(float));
  unsigned short* emb16 =
      (unsigned short*)((char*)perm + (((size_t)nperm * 4 + 15) & ~(size_t)15));

  prep_kernel<<<513, 1024, 0, stream>>>(emb, (unsigned int*)emb16, nemb / 8,
                                        aspect, B, perm, nperm);
  pool_kernel<<<(B + 3) / 4, 256, 0, stream>>>(ids, emb16, x, B);
  mlp_kernel<<<nperm / MTILE, 256, 0, stream>>>(x, aspect, perm, W1, b1, W2, b2, out);
}